// Round 7
// baseline (46.658 us; speedup 1.0000x reference)
//
#include <hip/hip_runtime.h>
#include <cstdint>

#define HD __device__ __forceinline__

constexpr int B = 4, N = 8192, H = 128, W = 128, K = 8;
constexpr float BIGF = 1e10f;
constexpr int NSTRIP = 16;           // vertical strips, 8 px wide each
constexpr int NBLK = B * NSTRIP;     // 64 blocks
constexpr int NTHR = 1024;           // 16 waves/block
constexpr int NBUCK = 16;            // 8-pixel-row buckets per strip
constexpr int BCAP = 240;            // per-bucket cap (E~46, ~28 sigma)

HD bool keyless(float z1, int i1, float z2, int i2) {
    return (z1 < z2) || ((z1 == z2) && (i1 < i2));
}

// branchless unrolled insert into ascending (z,idx)-sorted top-K registers.
// Caller guarantees keyless(nz,ni, zk[K-1],ik[K-1]).
HD void insert_topk(float nz, int ni, float nd,
                    float (&zk)[K], int (&ik)[K], float (&dk)[K]) {
    bool lt[K];
#pragma unroll
    for (int j = 0; j < K; ++j) lt[j] = keyless(nz, ni, zk[j], ik[j]);
#pragma unroll
    for (int j = K - 1; j >= 1; --j) {
        if (lt[j]) {
            if (lt[j - 1]) { zk[j] = zk[j - 1]; ik[j] = ik[j - 1]; dk[j] = dk[j - 1]; }
            else           { zk[j] = nz;        ik[j] = ni;        dk[j] = nd; }
        }
    }
    if (lt[0]) { zk[0] = nz; ik[0] = ni; dk[0] = nd; }
}

HD void transform_point(const float* __restrict__ w2v, const float* __restrict__ p2n,
                        float x, float y, float z,
                        float& xn, float& yn, float& zn) {
    float pv[4];
#pragma unroll
    for (int j = 0; j < 4; ++j)
        pv[j] = x * w2v[0 * 4 + j] + y * w2v[1 * 4 + j] +
                z * w2v[2 * 4 + j] + 1.0f * w2v[3 * 4 + j];
    float viewz = pv[2];
    // q[2] is never used by the reference output; compute only q0, q1, q3.
    float q0 = pv[0] * p2n[0] + pv[1] * p2n[4] + pv[2] * p2n[8]  + pv[3] * p2n[12];
    float q1 = pv[0] * p2n[1] + pv[1] * p2n[5] + pv[2] * p2n[9]  + pv[3] * p2n[13];
    float q3 = pv[0] * p2n[3] + pv[1] * p2n[7] + pv[2] * p2n[11] + pv[3] * p2n[15];
    float sgn = (q3 >= 0.0f) ? 1.0f : -1.0f;
    float denom = sgn * fmaxf(fabsf(q3), 1e-6f);
    xn = q0 / denom;
    yn = q1 / denom;
    zn = viewz;
}

HD void write_out(float* __restrict__ out, int pix,
                  const float (&zk)[K], const int (&ik)[K], const float (&dk)[K]) {
    const size_t S = (size_t)B * H * W * K;
    size_t off = (size_t)pix * K;
    float fi[K], fz[K], fd[K];
#pragma unroll
    for (int j = 0; j < K; ++j) {
        bool valid = zk[j] < 0.5f * BIGF;
        fi[j] = valid ? (float)ik[j] : -1.0f;
        fz[j] = valid ? zk[j] : -1.0f;
        fd[j] = valid ? dk[j] : -1.0f;
    }
    float4* o0 = reinterpret_cast<float4*>(out + off);
    float4* o1 = reinterpret_cast<float4*>(out + S + off);
    float4* o2 = reinterpret_cast<float4*>(out + 2 * S + off);
    float4* o3 = reinterpret_cast<float4*>(out + 3 * S + off);
    o0[0] = make_float4(fi[0], fi[1], fi[2], fi[3]);
    o0[1] = make_float4(fi[4], fi[5], fi[6], fi[7]);
    o1[0] = make_float4(fz[0], fz[1], fz[2], fz[3]);
    o1[1] = make_float4(fz[4], fz[5], fz[6], fz[7]);
    o2[0] = make_float4(fi[0], fi[1], fi[2], fi[3]);
    o2[1] = make_float4(fi[4], fi[5], fi[6], fi[7]);
    o3[0] = make_float4(fd[0], fd[1], fd[2], fd[3]);
    o3[1] = make_float4(fd[4], fd[5], fd[6], fd[7]);
}

// One block = one (batch, 8-px-wide column strip). 1024 threads:
// phase 1: each thread transforms 8 of the batch's 8192 points and appends
// strip-overlapping hits (xn,yn,zn,idx) into the 1-2 LDS buckets (8 pixel
// rows each) their bbox touches, via LDS atomicAdd. phase 2: one thread per
// pixel; each wave is exactly one 8x8 subtile, so all 64 lanes stream the
// same bucket list (broadcast LDS reads) doing exact d2 tests + top-8 insert.
// Bucket order is nondeterministic, but selection is by the total order
// (z, idx) -> deterministic output. No workspace, no global atomics, 1 node.
__global__ __launch_bounds__(NTHR, 4) void strip_raster_kernel(
    const float* __restrict__ points, const float* __restrict__ w2v,
    const float* __restrict__ p2n, float* __restrict__ out) {
    int blk = blockIdx.x;            // 0..63
    int b = blk >> 4;                // batch
    int sx = blk & 15;               // strip (pixel cols [8*sx, 8*sx+7])
    int tid = threadIdx.x;           // 0..1023

    __shared__ float4 list[NBUCK][BCAP];   // 61440 B
    __shared__ int lcnt[NBUCK];

    if (tid < NBUCK) lcnt[tid] = 0;
    __syncthreads();

    // ---- phase 1: transform 8 points/thread, bucket strip hits ----
    {
        const float* pbase = points + (size_t)b * N * 3;
        const int wlo = sx * 8, whi = sx * 8 + 7;
        const float rb = 0.0201f;    // conservative bbox margin > RADIUS
#pragma unroll
        for (int k = 0; k < N / NTHR; ++k) {
            int c = tid + k * NTHR;
            float x = pbase[c * 3 + 0], y = pbase[c * 3 + 1], z = pbase[c * 3 + 2];
            float xn, yn, zn;
            transform_point(w2v, p2n, x, y, z, xn, yn, zn);
            if (!(zn > 0.0f)) continue;
            int wmin = (int)ceilf(((1.0f - xn) - rb) * 64.0f - 0.5f);
            int wmax = (int)floorf(((1.0f - xn) + rb) * 64.0f - 0.5f);
            int hmin = (int)ceilf(((1.0f - yn) - rb) * 64.0f - 0.5f);
            int hmax = (int)floorf(((1.0f - yn) + rb) * 64.0f - 0.5f);
            wmin = max(wmin, 0); wmax = min(wmax, W - 1);
            hmin = max(hmin, 0); hmax = min(hmax, H - 1);
            if (wmin > wmax || hmin > hmax) continue;
            if (wmax < wlo || wmin > whi) continue;
            float4 e = make_float4(xn, yn, zn, __int_as_float(c));
            int g0 = hmin >> 3, g1 = hmax >> 3;   // bbox <=3 px tall: <=2 buckets
            for (int g = g0; g <= g1; ++g) {
                int pos = atomicAdd(&lcnt[g], 1);
                if (pos < BCAP) list[g][pos] = e;
            }
        }
    }
    __syncthreads();

    // ---- phase 2: one thread per pixel, wave = one 8x8 subtile ----
    {
        int s = tid >> 6;            // bucket / subtile 0..15
        int lane = tid & 63;
        int h = s * 8 + (lane >> 3);
        int w = sx * 8 + (lane & 7);
        float px = 1.0f - (2.0f * (float)w + 1.0f) / 128.0f;
        float py = 1.0f - (2.0f * (float)h + 1.0f) / 128.0f;
        const float r2 = (float)(0.02 * 0.02);

        int c = lcnt[s];
        if (c > BCAP) c = BCAP;

        float zk[K]; int ik[K]; float dk[K];
#pragma unroll
        for (int j = 0; j < K; ++j) { zk[j] = BIGF; ik[j] = 0x7fffffff; dk[j] = 0.0f; }

        for (int j = 0; j < c; ++j) {
            float4 e = list[s][j];   // broadcast: all lanes read same address
            float dx = e.x - px, dy = e.y - py;
            float d2 = __fadd_rn(__fmul_rn(dx, dx), __fmul_rn(dy, dy));
            int pi = __float_as_int(e.w);
            if ((d2 <= r2) && keyless(e.z, pi, zk[K - 1], ik[K - 1]))
                insert_topk(e.z, pi, d2, zk, ik, dk);
        }
        int pix = (b << 14) + (h << 7) + w;
        write_out(out, pix, zk, ik, dk);
    }
}

extern "C" void kernel_launch(void* const* d_in, const int* in_sizes, int n_in,
                              void* d_out, int out_size, void* d_ws, size_t ws_size,
                              hipStream_t stream) {
    const float* points = (const float*)d_in[0];
    const float* w2v    = (const float*)d_in[1];
    const float* p2n    = (const float*)d_in[2];
    float* out = (float*)d_out;
    (void)d_ws; (void)ws_size;

    strip_raster_kernel<<<NBLK, NTHR, 0, stream>>>(points, w2v, p2n, out);
}

// Round 8
// 41.628 us; speedup vs baseline: 1.1208x; 1.1208x over previous
//
#include <hip/hip_runtime.h>
#include <cstdint>

#define HD __device__ __forceinline__

constexpr int B = 4, N = 8192, H = 128, W = 128, K = 8;
constexpr float BIGF = 1e10f;
constexpr int NTHR = 1024;           // 16 waves/block
constexpr int NBLK = 256;            // 4 batches x 64 tiles (8x8 grid of 16x16 px)
constexpr int BCAP = 256;            // per-subtile bucket cap (E~56, 26 sigma)

HD bool keyless(float z1, int i1, float z2, int i2) {
    return (z1 < z2) || ((z1 == z2) && (i1 < i2));
}

// branchless unrolled insert into ascending (z,idx)-sorted top-K registers.
// Caller guarantees keyless(nz,ni, zk[K-1],ik[K-1]).
HD void insert_topk(float nz, int ni, float nd,
                    float (&zk)[K], int (&ik)[K], float (&dk)[K]) {
    bool lt[K];
#pragma unroll
    for (int j = 0; j < K; ++j) lt[j] = keyless(nz, ni, zk[j], ik[j]);
#pragma unroll
    for (int j = K - 1; j >= 1; --j) {
        if (lt[j]) {
            if (lt[j - 1]) { zk[j] = zk[j - 1]; ik[j] = ik[j - 1]; dk[j] = dk[j - 1]; }
            else           { zk[j] = nz;        ik[j] = ni;        dk[j] = nd; }
        }
    }
    if (lt[0]) { zk[0] = nz; ik[0] = ni; dk[0] = nd; }
}

HD void write_out(float* __restrict__ out, int pix,
                  const float (&zk)[K], const int (&ik)[K], const float (&dk)[K]) {
    const size_t S = (size_t)B * H * W * K;
    size_t off = (size_t)pix * K;
    float fi[K], fz[K], fd[K];
#pragma unroll
    for (int j = 0; j < K; ++j) {
        bool valid = zk[j] < 0.5f * BIGF;
        fi[j] = valid ? (float)ik[j] : -1.0f;
        fz[j] = valid ? zk[j] : -1.0f;
        fd[j] = valid ? dk[j] : -1.0f;
    }
    float4* o0 = reinterpret_cast<float4*>(out + off);
    float4* o1 = reinterpret_cast<float4*>(out + S + off);
    float4* o2 = reinterpret_cast<float4*>(out + 2 * S + off);
    float4* o3 = reinterpret_cast<float4*>(out + 3 * S + off);
    o0[0] = make_float4(fi[0], fi[1], fi[2], fi[3]);
    o0[1] = make_float4(fi[4], fi[5], fi[6], fi[7]);
    o1[0] = make_float4(fz[0], fz[1], fz[2], fz[3]);
    o1[1] = make_float4(fz[4], fz[5], fz[6], fz[7]);
    o2[0] = make_float4(fi[0], fi[1], fi[2], fi[3]);
    o2[1] = make_float4(fi[4], fi[5], fi[6], fi[7]);
    o3[0] = make_float4(fd[0], fd[1], fd[2], fd[3]);
    o3[1] = make_float4(fd[4], fd[5], fd[6], fd[7]);
}

// One block = one (batch, 16x16-px tile). 1024 threads.
// Phase 0: 16 threads build the combined matrix C = w2v @ p2n (cols 0,1,3)
//   plus w2v col 2 (view z) in LDS. With w2v = eye this is bitwise p2n, so
//   q = ph @ C matches the reference's (ph @ w2v) @ p2n arithmetic.
// Phase 1: each thread transforms 8 of the batch's 8192 points. Reject test
//   is division-free: den > 0 always, so xn in [xlo,xhi] <=> q0 in
//   [xlo*den, xhi*den] (margin 1e-4 NDC >> mul rounding). Hits (~0.17%)
//   compute xn = q0/den (bitwise reference), the pixel bbox, and append to
//   the 1-4 per-8x8-subtile LDS buckets their bbox touches (LDS atomicAdd).
// Phase 2: 4 waves; wave = subtile, lane = pixel; ~56 broadcast LDS reads,
//   exact d2 test + top-8 insert by the total order (z, idx) -> output is
//   deterministic despite nondeterministic bucket order.
// No workspace, no global atomics, one graph node.
__global__ __launch_bounds__(NTHR, 4) void tile_raster_kernel(
    const float* __restrict__ points, const float* __restrict__ w2v,
    const float* __restrict__ p2n, float* __restrict__ out) {
    int blk = blockIdx.x;            // 0..255
    int b = blk >> 6;                // batch
    int ti = blk & 63;
    int ty = ti >> 3, tx = ti & 7;   // 8x8 grid of 16x16-px tiles
    int tid = threadIdx.x;           // 0..1023

    __shared__ float lc[16];         // C cols 0,1,3 (rows 0..3 each) + W col 2
    __shared__ float4 list[4][BCAP]; // 16 KB
    __shared__ int lcnt[4];

    if (tid < 16) {
        int r = tid & 3, sel = tid >> 2;
        float v;
        if (sel < 3) {
            int j = (sel == 0) ? 0 : (sel == 1) ? 1 : 3;
            v = w2v[r * 4 + 0] * p2n[0 * 4 + j] + w2v[r * 4 + 1] * p2n[1 * 4 + j] +
                w2v[r * 4 + 2] * p2n[2 * 4 + j] + w2v[r * 4 + 3] * p2n[3 * 4 + j];
        } else {
            v = w2v[r * 4 + 2];      // view-z column
        }
        lc[tid] = v;
        if (tid < 4) lcnt[tid] = 0;
    }
    __syncthreads();

    float a0 = lc[0],  a1 = lc[1],  a2 = lc[2],  a3 = lc[3];   // q0 coeffs
    float b0 = lc[4],  b1 = lc[5],  b2 = lc[6],  b3 = lc[7];   // q1 coeffs
    float d0 = lc[8],  d1 = lc[9],  d2c = lc[10], d3 = lc[11]; // q3 coeffs
    float e0 = lc[12], e1 = lc[13], e2 = lc[14], e3 = lc[15];  // viewz coeffs

    const int W0 = tx * 16, H0 = ty * 16;
    const float rb = 0.0201f;        // conservative margin > RADIUS
    // tile pixel-center NDC bounds (px decreases with w, py with h)
    float pxhi = 1.0f - (2.0f * (float)W0 + 1.0f) / 128.0f;
    float pxlo = 1.0f - (2.0f * (float)(W0 + 15) + 1.0f) / 128.0f;
    float pyhi = 1.0f - (2.0f * (float)H0 + 1.0f) / 128.0f;
    float pylo = 1.0f - (2.0f * (float)(H0 + 15) + 1.0f) / 128.0f;
    float xlo = pxlo - rb, xhi = pxhi + rb;
    float ylo = pylo - rb, yhi = pyhi + rb;

    // ---- phase 1: transform 8 points/thread, bucket tile hits ----
    {
        const float* pbase = points + (size_t)b * N * 3;
#pragma unroll
        for (int k = 0; k < N / NTHR; ++k) {
            int c = tid + k * NTHR;
            float x = pbase[c * 3 + 0], y = pbase[c * 3 + 1], z = pbase[c * 3 + 2];
            float q0 = x * a0 + y * a1 + z * a2 + a3;
            float q1 = x * b0 + y * b1 + z * b2 + b3;
            float q3 = x * d0 + y * d1 + z * d2c + d3;
            float zn = x * e0 + y * e1 + z * e2 + e3;
            float sgn = (q3 >= 0.0f) ? 1.0f : -1.0f;
            float den = sgn * fmaxf(fabsf(q3), 1e-6f);   // always > 0
            bool hit = (zn > 0.0f) &&
                       (q0 >= xlo * den) && (q0 <= xhi * den) &&
                       (q1 >= ylo * den) && (q1 <= yhi * den);
            if (hit) {
                float xn = q0 / den, yn = q1 / den;      // bitwise = reference
                int wmin = (int)ceilf(((1.0f - xn) - rb) * 64.0f - 0.5f);
                int wmax = (int)floorf(((1.0f - xn) + rb) * 64.0f - 0.5f);
                int hmin = (int)ceilf(((1.0f - yn) - rb) * 64.0f - 0.5f);
                int hmax = (int)floorf(((1.0f - yn) + rb) * 64.0f - 0.5f);
                int lx0 = max(wmin - W0, 0), lx1 = min(wmax - W0, 15);
                int ly0 = max(hmin - H0, 0), ly1 = min(hmax - H0, 15);
                if (lx0 <= lx1 && ly0 <= ly1) {
                    float4 e4 = make_float4(xn, yn, zn, __int_as_float(c));
                    for (int sy = ly0 >> 3; sy <= ly1 >> 3; ++sy)
                        for (int sx = lx0 >> 3; sx <= lx1 >> 3; ++sx) {
                            int bk = sy * 2 + sx;
                            int pos = atomicAdd(&lcnt[bk], 1);
                            if (pos < BCAP) list[bk][pos] = e4;
                        }
                }
            }
        }
    }
    __syncthreads();

    // ---- phase 2: 4 waves; wave = 8x8 subtile, lane = pixel ----
    if (tid < 256) {
        int s = tid >> 6, lane = tid & 63;
        int sy = s >> 1, sx = s & 1;
        int hh = H0 + sy * 8 + (lane >> 3);
        int ww = W0 + sx * 8 + (lane & 7);
        float px = 1.0f - (2.0f * (float)ww + 1.0f) / 128.0f;
        float py = 1.0f - (2.0f * (float)hh + 1.0f) / 128.0f;
        const float r2 = (float)(0.02 * 0.02);

        int cnt = lcnt[s];
        if (cnt > BCAP) cnt = BCAP;

        float zk[K]; int ik[K]; float dk[K];
#pragma unroll
        for (int j = 0; j < K; ++j) { zk[j] = BIGF; ik[j] = 0x7fffffff; dk[j] = 0.0f; }

        for (int j = 0; j < cnt; ++j) {
            float4 e = list[s][j];   // broadcast: all lanes read same address
            float dx = e.x - px, dy = e.y - py;
            float dd = __fadd_rn(__fmul_rn(dx, dx), __fmul_rn(dy, dy));
            int pi = __float_as_int(e.w);
            if ((dd <= r2) && keyless(e.z, pi, zk[K - 1], ik[K - 1]))
                insert_topk(e.z, pi, dd, zk, ik, dk);
        }
        int pix = (b << 14) + (hh << 7) + ww;
        write_out(out, pix, zk, ik, dk);
    }
}

extern "C" void kernel_launch(void* const* d_in, const int* in_sizes, int n_in,
                              void* d_out, int out_size, void* d_ws, size_t ws_size,
                              hipStream_t stream) {
    const float* points = (const float*)d_in[0];
    const float* w2v    = (const float*)d_in[1];
    const float* p2n    = (const float*)d_in[2];
    float* out = (float*)d_out;
    (void)d_ws; (void)ws_size;

    tile_raster_kernel<<<NBLK, NTHR, 0, stream>>>(points, w2v, p2n, out);
}

// Round 9
// 39.294 us; speedup vs baseline: 1.1874x; 1.0594x over previous
//
#include <hip/hip_runtime.h>
#include <cstdint>

#define HD __device__ __forceinline__

constexpr int B = 4, N = 8192, H = 128, W = 128, K = 8;
constexpr float BIGF = 1e10f;
constexpr int NBLK2 = 1024;          // 4 batches x 256 tiles (16x16 of 8x8 px)
constexpr int NTHR2 = 256;           // 4 waves/block
constexpr int LCAP = 512;            // LDS candidate cap (E~56, ~61 sigma)

HD bool keyless(float z1, int i1, float z2, int i2) {
    return (z1 < z2) || ((z1 == z2) && (i1 < i2));
}

// branchless unrolled insert into ascending (z,idx)-sorted top-K registers.
// Caller guarantees keyless(nz,ni, zk[K-1],ik[K-1]).
HD void insert_topk(float nz, int ni, float nd,
                    float (&zk)[K], int (&ik)[K], float (&dk)[K]) {
    bool lt[K];
#pragma unroll
    for (int j = 0; j < K; ++j) lt[j] = keyless(nz, ni, zk[j], ik[j]);
#pragma unroll
    for (int j = K - 1; j >= 1; --j) {
        if (lt[j]) {
            if (lt[j - 1]) { zk[j] = zk[j - 1]; ik[j] = ik[j - 1]; dk[j] = dk[j - 1]; }
            else           { zk[j] = nz;        ik[j] = ni;        dk[j] = nd; }
        }
    }
    if (lt[0]) { zk[0] = nz; ik[0] = ni; dk[0] = nd; }
}

HD void write_out(float* __restrict__ out, int pix,
                  const float (&zk)[K], const int (&ik)[K], const float (&dk)[K]) {
    const size_t S = (size_t)B * H * W * K;
    size_t off = (size_t)pix * K;
    float fi[K], fz[K], fd[K];
#pragma unroll
    for (int j = 0; j < K; ++j) {
        bool valid = zk[j] < 0.5f * BIGF;
        fi[j] = valid ? (float)ik[j] : -1.0f;
        fz[j] = valid ? zk[j] : -1.0f;
        fd[j] = valid ? dk[j] : -1.0f;
    }
    float4* o0 = reinterpret_cast<float4*>(out + off);
    float4* o1 = reinterpret_cast<float4*>(out + S + off);
    float4* o2 = reinterpret_cast<float4*>(out + 2 * S + off);
    float4* o3 = reinterpret_cast<float4*>(out + 3 * S + off);
    o0[0] = make_float4(fi[0], fi[1], fi[2], fi[3]);
    o0[1] = make_float4(fi[4], fi[5], fi[6], fi[7]);
    o1[0] = make_float4(fz[0], fz[1], fz[2], fz[3]);
    o1[1] = make_float4(fz[4], fz[5], fz[6], fz[7]);
    o2[0] = make_float4(fi[0], fi[1], fi[2], fi[3]);
    o2[1] = make_float4(fi[4], fi[5], fi[6], fi[7]);
    o3[0] = make_float4(fd[0], fd[1], fd[2], fd[3]);
    o3[1] = make_float4(fd[4], fd[5], fd[6], fd[7]);
}

// ---------------- node 1: transform all points once into staged NDC --------
// Arithmetic is bitwise-identical to the passing round-8 kernel: combined
// matrix C = w2v @ p2n (cols 0,1,3) + w2v col 2 built in LDS by 16 threads,
// then q0,q1,q3,viewz + sign-clamped divide. zn <= 0 gets a sentinel x that
// fails every tile bbox test.
__global__ __launch_bounds__(256) void transform_stage_kernel(
    const float* __restrict__ points, const float* __restrict__ w2v,
    const float* __restrict__ p2n, float4* __restrict__ staged) {
    __shared__ float lc[16];
    int tid = threadIdx.x;
    if (tid < 16) {
        int r = tid & 3, sel = tid >> 2;
        float v;
        if (sel < 3) {
            int j = (sel == 0) ? 0 : (sel == 1) ? 1 : 3;
            v = w2v[r * 4 + 0] * p2n[0 * 4 + j] + w2v[r * 4 + 1] * p2n[1 * 4 + j] +
                w2v[r * 4 + 2] * p2n[2 * 4 + j] + w2v[r * 4 + 3] * p2n[3 * 4 + j];
        } else {
            v = w2v[r * 4 + 2];      // view-z column
        }
        lc[tid] = v;
    }
    __syncthreads();

    int gid = blockIdx.x * 256 + tid;    // 0..B*N-1 (grid sized exactly)
    float x = points[(size_t)gid * 3 + 0];
    float y = points[(size_t)gid * 3 + 1];
    float z = points[(size_t)gid * 3 + 2];
    float q0 = x * lc[0]  + y * lc[1]  + z * lc[2]  + lc[3];
    float q1 = x * lc[4]  + y * lc[5]  + z * lc[6]  + lc[7];
    float q3 = x * lc[8]  + y * lc[9]  + z * lc[10] + lc[11];
    float zn = x * lc[12] + y * lc[13] + z * lc[14] + lc[15];
    float sgn = (q3 >= 0.0f) ? 1.0f : -1.0f;
    float den = sgn * fmaxf(fabsf(q3), 1e-6f);   // always > 0
    float xn = q0 / den, yn = q1 / den;
    if (!(zn > 0.0f)) xn = 1e30f;                // sentinel: fails bbox
    staged[gid] = make_float4(xn, yn, zn, 0.0f);
}

// ---------------- node 2: per-tile gather + exact top-8 --------------------
// One block = one 8x8-px tile of one batch. 4 waves scan the batch's 8192
// staged points (32 float4 loads/thread, ~10 instr tests), ballot-compact
// tile hits (~56) into LDS, then 4 threads/pixel build partial top-8s over
// strided subsets and wave 0 merges 4x8 -> 8 per pixel. Selection is by the
// total order (z, idx) -> deterministic despite nondeterministic list order.
__global__ __launch_bounds__(NTHR2, 4) void tile_gather_kernel(
    const float4* __restrict__ staged, float* __restrict__ out) {
    int blk = blockIdx.x;            // 0..1023
    int b = blk >> 8;                // 256 tiles per batch
    int ti = blk & 255;
    int ty = ti >> 4, tx = ti & 15;
    int tid = threadIdx.x;           // 0..255
    int lane = tid & 63;

    const float rb = 0.0201f;        // conservative margin > RADIUS
    float pxmax = 1.0f - (float)(16 * tx + 1) / 128.0f;
    float pxmin = pxmax - 14.0f / 128.0f;
    float pymax = 1.0f - (float)(16 * ty + 1) / 128.0f;
    float pymin = pymax - 14.0f / 128.0f;
    float xlo = pxmin - rb, xhi = pxmax + rb;
    float ylo = pymin - rb, yhi = pymax + rb;

    __shared__ float4 list[LCAP];    // 8 KB
    __shared__ int lcnt;
    __shared__ float smz[64][33];    // +1 pad: conflict-free merge reads
    __shared__ int   smi[64][33];
    __shared__ float smd[64][33];

    if (tid == 0) lcnt = 0;
    __syncthreads();

    // ---- scan + compaction ----
    const float4* base = staged + (size_t)b * N;
    const unsigned long long lmask_lt = (1ull << lane) - 1ull;
    for (int c = tid; c < N; c += NTHR2) {
        float4 e = base[c];
        bool hit = (e.x >= xlo) && (e.x <= xhi) && (e.y >= ylo) && (e.y <= yhi);
        unsigned long long m = __ballot(hit);
        int wcnt = (int)__popcll(m);
        int wbase = 0;
        if (lane == 0 && wcnt) wbase = atomicAdd(&lcnt, wcnt);
        wbase = __shfl(wbase, 0);
        if (hit) {
            int pos = wbase + (int)__popcll(m & lmask_lt);
            if (pos < LCAP) {
                e.w = __int_as_float(c);
                list[pos] = e;
            }
        }
    }
    __syncthreads();
    int cl = lcnt;
    if (cl > LCAP) cl = LCAP;

    // ---- partial top-8: 4 threads per pixel, strided candidates ----
    int p = tid >> 2, q = tid & 3;
    int w = tx * 8 + (p & 7);
    int h = ty * 8 + (p >> 3);
    float px = 1.0f - (2.0f * (float)w + 1.0f) / 128.0f;
    float py = 1.0f - (2.0f * (float)h + 1.0f) / 128.0f;
    const float r2 = (float)(0.02 * 0.02);

    float zk[K]; int ik[K]; float dk[K];
#pragma unroll
    for (int j = 0; j < K; ++j) { zk[j] = BIGF; ik[j] = 0x7fffffff; dk[j] = 0.0f; }

    for (int j = q; j < cl; j += 4) {
        float4 e = list[j];          // 4 distinct addrs/wave, 16-way broadcast
        float dx = e.x - px, dy = e.y - py;
        float d2 = __fadd_rn(__fmul_rn(dx, dx), __fmul_rn(dy, dy));
        int pi = __float_as_int(e.w);
        if ((d2 <= r2) && keyless(e.z, pi, zk[K - 1], ik[K - 1]))
            insert_topk(e.z, pi, d2, zk, ik, dk);
    }
#pragma unroll
    for (int k = 0; k < K; ++k) {
        smz[p][q * 8 + k] = zk[k];
        smi[p][q * 8 + k] = ik[k];
        smd[p][q * 8 + k] = dk[k];
    }
    __syncthreads();

    // ---- merge 4 partials per pixel (wave 0), write out ----
    if (tid < 64) {
#pragma unroll
        for (int j = 0; j < K; ++j) { zk[j] = BIGF; ik[j] = 0x7fffffff; dk[j] = 0.0f; }
        for (int j = 0; j < 32; ++j) {
            float z = smz[tid][j];
            int i = smi[tid][j];
            if (keyless(z, i, zk[K - 1], ik[K - 1]))
                insert_topk(z, i, smd[tid][j], zk, ik, dk);
        }
        int ww = tx * 8 + (tid & 7);
        int hh = ty * 8 + (tid >> 3);
        int pix = (b << 14) + (hh << 7) + ww;
        write_out(out, pix, zk, ik, dk);
    }
}

// ---------------- fallback: brute force (no workspace needed) ----------------
HD void transform_point_full(const float* __restrict__ w2v, const float* __restrict__ p2n,
                             float x, float y, float z,
                             float& xn, float& yn, float& zn) {
    float pv[4];
#pragma unroll
    for (int j = 0; j < 4; ++j)
        pv[j] = x * w2v[0 * 4 + j] + y * w2v[1 * 4 + j] +
                z * w2v[2 * 4 + j] + 1.0f * w2v[3 * 4 + j];
    float viewz = pv[2];
    float q0 = pv[0] * p2n[0] + pv[1] * p2n[4] + pv[2] * p2n[8]  + pv[3] * p2n[12];
    float q1 = pv[0] * p2n[1] + pv[1] * p2n[5] + pv[2] * p2n[9]  + pv[3] * p2n[13];
    float q3 = pv[0] * p2n[3] + pv[1] * p2n[7] + pv[2] * p2n[11] + pv[3] * p2n[15];
    float sgn = (q3 >= 0.0f) ? 1.0f : -1.0f;
    float den = sgn * fmaxf(fabsf(q3), 1e-6f);
    xn = q0 / den; yn = q1 / den; zn = viewz;
}

__global__ __launch_bounds__(256) void brute_kernel(
    const float* __restrict__ points, const float* __restrict__ w2v,
    const float* __restrict__ p2n, float* __restrict__ out) {
    int gid = blockIdx.x * 256 + threadIdx.x;   // 0..B*H*W-1
    int b = gid >> 14;
    float px = 1.0f - (2.0f * (float)(gid & 127) + 1.0f) / 128.0f;
    float py = 1.0f - (2.0f * (float)((gid >> 7) & 127) + 1.0f) / 128.0f;
    const float r2 = (float)(0.02 * 0.02);

    __shared__ float4 sh[256];

    float zk[K]; int ik[K]; float dk[K];
#pragma unroll
    for (int j = 0; j < K; ++j) { zk[j] = BIGF; ik[j] = 0x7fffffff; dk[j] = 0.0f; }

    for (int c = 0; c < N; c += 256) {
        __syncthreads();
        int n = c + threadIdx.x;
        float x = points[((size_t)b * N + n) * 3 + 0];
        float y = points[((size_t)b * N + n) * 3 + 1];
        float z = points[((size_t)b * N + n) * 3 + 2];
        float xn, yn, zn;
        transform_point_full(w2v, p2n, x, y, z, xn, yn, zn);
        sh[threadIdx.x] = make_float4(xn, yn, zn, __int_as_float(n));
        __syncthreads();
        for (int e = 0; e < 256; ++e) {
            float4 pe = sh[e];
            float dx = pe.x - px, dy = pe.y - py;
            float d2 = __fadd_rn(__fmul_rn(dx, dx), __fmul_rn(dy, dy));
            int pi = __float_as_int(pe.w);
            if ((d2 <= r2) && (pe.z > 0.0f) && keyless(pe.z, pi, zk[K - 1], ik[K - 1]))
                insert_topk(pe.z, pi, d2, zk, ik, dk);
        }
    }
    write_out(out, gid, zk, ik, dk);
}

extern "C" void kernel_launch(void* const* d_in, const int* in_sizes, int n_in,
                              void* d_out, int out_size, void* d_ws, size_t ws_size,
                              hipStream_t stream) {
    const float* points = (const float*)d_in[0];
    const float* w2v    = (const float*)d_in[1];
    const float* p2n    = (const float*)d_in[2];
    float* out = (float*)d_out;

    const size_t need = (size_t)B * N * sizeof(float4);   // 512 KB staged
    if (ws_size >= need) {
        float4* staged = (float4*)d_ws;
        transform_stage_kernel<<<(B * N) / 256, 256, 0, stream>>>(points, w2v, p2n, staged);
        tile_gather_kernel<<<NBLK2, NTHR2, 0, stream>>>(staged, out);
    } else {
        brute_kernel<<<(B * H * W) / 256, 256, 0, stream>>>(points, w2v, p2n, out);
    }
}